// Round 2
// baseline (1331.823 us; speedup 1.0000x reference)
//
#include <hip/hip_runtime.h>
#include <math.h>

#define NUM_PIDS 30000
#define CQ_SIZE  8192
#define BATCH    2048
#define FEAT     256
#define EPS_BN   1e-5f
#define EPS_NORM 1e-12f
#define SCALARV  30.0f

// padded column space: [0,30000) lut, [30000,30080) pad, [30080,38272) cq
#define LUT_PAD  30080
#define NCOL     38272
#define NTILES   299      // 235 lut tiles + 64 cq tiles (128 cols each)
#define LUT_TILES 235
#define SLICES   23
#define TPS      13       // 23*13 = 299 exactly
#define BR       64
#define BC       128
#define NB1      120      // stats blocks, 250 lut rows each

// workspace layout (float element offsets)
#define WS_Q1    0
#define WS_Q2    (WS_Q1 + BATCH*FEAT)
#define WS_CB1   (WS_Q2 + BATCH*FEAT)
#define WS_CB2   (WS_CB1 + BATCH)
#define WS_RN2   (WS_CB2 + BATCH)          // float2 per column: {rn, cap}
#define WS_FLAGS (WS_RN2 + 2*NCOL)         // int32, lut rows only
#define WS_PSUM  (WS_FLAGS + LUT_PAD)
#define WS_PSQ   (WS_PSUM + NB1*FEAT)
#define WS_PCNT  (WS_PSQ + NB1*FEAT)
#define WS_A1    (WS_PCNT + 128)
#define WS_B1    (WS_A1 + FEAT)
#define WS_A2    (WS_B1 + FEAT)
#define WS_B2    (WS_A2 + FEAT)
#define WS_ZT    (WS_B2 + FEAT)
#define WS_PART  (WS_ZT + BATCH)           // BATCH*SLICES floats

// ---------------- stats pass 1: per-block partial sums over good lut rows ----
__global__ __launch_bounds__(256) void k_stats1(const float* __restrict__ lut,
                                                float* __restrict__ ws,
                                                int* __restrict__ flags) {
  const int t = threadIdx.x;
  const int rbase = blockIdx.x * 250;
  __shared__ unsigned char wz[250 * 4];
  for (int i = 0; i < 250; ++i) {
    float v = lut[(size_t)(rbase + i) * FEAT + t];
    unsigned long long bal = __ballot(v != 0.0f);
    if ((t & 63) == 0) wz[i * 4 + (t >> 6)] = (bal != 0ull) ? 1 : 0;
  }
  __syncthreads();
  for (int i = t; i < 250; i += 256) {
    int bad = !(wz[i*4] | wz[i*4+1] | wz[i*4+2] | wz[i*4+3]);
    flags[rbase + i] = bad;
  }
  float s = 0.f, sq = 0.f; int cnt = 0;
  for (int i = 0; i < 250; ++i) {
    int bad = !(wz[i*4] | wz[i*4+1] | wz[i*4+2] | wz[i*4+3]);
    if (!bad) {
      float v = lut[(size_t)(rbase + i) * FEAT + t];
      s += v; sq += v * v; ++cnt;
    }
  }
  ws[WS_PSUM + blockIdx.x * FEAT + t] = s;
  ws[WS_PSQ  + blockIdx.x * FEAT + t] = sq;
  if (t == 0) ws[WS_PCNT + blockIdx.x] = (float)cnt;
}

// ---------------- stats pass 2: mean/var -> affine coeffs; pad rn2 ----------
__global__ __launch_bounds__(256) void k_stats2(const float* __restrict__ bnw,
                                                const float* __restrict__ bnb,
                                                float* __restrict__ ws) {
  const int t = threadIdx.x;
  float2* rn2 = (float2*)(ws + WS_RN2);
  float s = 0.f, sq = 0.f, n = 0.f;
  for (int b = 0; b < NB1; ++b) { s += ws[WS_PSUM + b*FEAT + t]; sq += ws[WS_PSQ + b*FEAT + t]; }
  for (int b = 0; b < NB1; ++b) n += ws[WS_PCNT + b];
  float mean = s / n;
  float var = fmaxf(sq / n - mean * mean, 0.f);
  float istd_b = rsqrtf(var + EPS_BN);
  float rv1 = var * n / (n - 1.f);
  float istd_u = rsqrtf(rv1 + EPS_BN);
  float w = bnw[t], b_ = bnb[t];
  float a1 = istd_b * w, a2 = istd_u * w;
  ws[WS_A1 + t] = a1; ws[WS_B1 + t] = b_ - mean * a1;
  ws[WS_A2 + t] = a2; ws[WS_B2 + t] = b_ - mean * a2;
  if (t < (LUT_PAD - NUM_PIDS)) rn2[NUM_PIDS + t] = make_float2(0.f, -1e30f);  // pads: 0 weight
}

// ---------------- qn + q1/q2 + per-row scalars cB1/cB2 ----------------------
__global__ __launch_bounds__(256) void k_qn(const float* __restrict__ inp,
                                            const float* __restrict__ bnw,
                                            const float* __restrict__ bnb,
                                            float* __restrict__ ws) {
  const int r = blockIdx.x, t = threadIdx.x;
  const float s0 = rsqrtf(1.0f + EPS_BN);
  float v = inp[(size_t)r * FEAT + t];
  float bn = v * (bnw[t] * s0) + bnb[t];
  float x = bn * bn;
  for (int o = 32; o; o >>= 1) x += __shfl_down(x, o);
  __shared__ float w4[4];
  __shared__ float w8[8];
  if ((t & 63) == 0) w4[t >> 6] = x;
  __syncthreads();
  float nsq = w4[0] + w4[1] + w4[2] + w4[3];
  float rinv = 1.0f / fmaxf(sqrtf(nsq), EPS_NORM);
  float qn = bn * rinv;
  float y1 = qn * ws[WS_B1 + t], y2 = qn * ws[WS_B2 + t];
  for (int o = 32; o; o >>= 1) { y1 += __shfl_down(y1, o); y2 += __shfl_down(y2, o); }
  if ((t & 63) == 0) { w8[t >> 6] = y1; w8[4 + (t >> 6)] = y2; }
  ws[WS_Q1 + (size_t)r * FEAT + t] = qn * ws[WS_A1 + t];
  ws[WS_Q2 + (size_t)r * FEAT + t] = qn * ws[WS_A2 + t];
  __syncthreads();
  if (t == 0) {
    ws[WS_CB1 + r] = w8[0] + w8[1] + w8[2] + w8[3];
    ws[WS_CB2 + r] = w8[4] + w8[5] + w8[6] + w8[7];
  }
}

// ---------------- per-column {rn, cap} (float2) -----------------------------
__global__ __launch_bounds__(256) void k_norms(const float* __restrict__ lut,
                                               const float* __restrict__ cq,
                                               float* __restrict__ ws) {
  const int t = threadIdx.x;
  const int row = blockIdx.x;  // 0..38191
  float2* rn2 = (float2*)(ws + WS_RN2);
  const int* flags = (const int*)(ws + WS_FLAGS);
  float a, b, v; int cidx, bad;
  __shared__ unsigned char wzs[4];
  __shared__ float w4[4];
  if (row < NUM_PIDS) {
    v = lut[(size_t)row * FEAT + t];
    a = ws[WS_A1 + t]; b = ws[WS_B1 + t];
    cidx = row;
    bad = flags[row];
  } else {
    int q = row - NUM_PIDS;
    v = cq[(size_t)q * FEAT + t];
    a = ws[WS_A2 + t]; b = ws[WS_B2 + t];
    cidx = LUT_PAD + q;
    unsigned long long bal = __ballot(v != 0.0f);
    if ((t & 63) == 0) wzs[t >> 6] = (bal != 0ull) ? 1 : 0;
    __syncthreads();
    bad = !(wzs[0] | wzs[1] | wzs[2] | wzs[3]);
  }
  float bn = bad ? 0.f : (v * a + b);
  float x = bn * bn;
  for (int o = 32; o; o >>= 1) x += __shfl_down(x, o);
  if ((t & 63) == 0) w4[t >> 6] = x;
  __syncthreads();
  if (t == 0) {
    float nrm = sqrtf(w4[0] + w4[1] + w4[2] + w4[3]);
    // bad column: raw row is all-zero so staged acc=0; rn=0 gives z=0, cap -30
    // reproduces the reference's exact -1*SCALAR logit via fminf.
    rn2[cidx] = bad ? make_float2(0.f, -SCALARV)
                    : make_float2(1.0f / fmaxf(nrm, EPS_NORM), 1e30f);
  }
}

// ---------------- fused GEMM + fixed-max(30) sumexp -------------------------
__global__ __launch_bounds__(256) void k_gemm(const float* __restrict__ lut,
                                              const float* __restrict__ cq,
                                              float* __restrict__ ws) {
  const int tid = threadIdx.x;
  const int slice = blockIdx.x;      // 0..22
  const int rowbase = blockIdx.y * BR;
  const int tc = tid & 15, tr = tid >> 4;
  const int r0 = tr * 4, c0 = tc * 8;
  const float2* rn2 = (const float2*)(ws + WS_RN2);

  __shared__ __align__(16) float qs[BR * 68];
  __shared__ __align__(16) float xs[BC * 68];

  float s[4], cb1[4], cb2[4];
#pragma unroll
  for (int i = 0; i < 4; ++i) {
    s[i] = 0.f;
    cb1[i] = ws[WS_CB1 + rowbase + r0 + i];
    cb2[i] = ws[WS_CB2 + rowbase + r0 + i];
  }

  const int t0 = slice * TPS;
  for (int tix = t0; tix < t0 + TPS; ++tix) {
    const bool islut = (tix < LUT_TILES);
    const int colbase = tix * BC;
    const float* srcQ = ws + (islut ? WS_Q1 : WS_Q2);
    float acc[4][8];
#pragma unroll
    for (int i = 0; i < 4; ++i)
#pragma unroll
      for (int j = 0; j < 8; ++j) acc[i][j] = 0.f;

    for (int kc = 0; kc < 4; ++kc) {
      const int k0 = kc * 64;
#pragma unroll
      for (int it = 0; it < 4; ++it) {           // stage Q tile: 64 rows x 64 k
        int idx = it * 256 + tid;
        int row = idx >> 4, k4 = idx & 15;
        float4 v = *(const float4*)&srcQ[(size_t)(rowbase + row) * FEAT + k0 + 4 * k4];
        *(float4*)&qs[row * 68 + 4 * k4] = v;
      }
#pragma unroll
      for (int it = 0; it < 8; ++it) {           // stage X tile: 128 cols x 64 k
        int idx = it * 256 + tid;
        int col = idx >> 4, k4 = idx & 15;
        int c = colbase + col;
        float4 v = make_float4(0.f, 0.f, 0.f, 0.f);
        if (islut) {
          if (c < NUM_PIDS) v = *(const float4*)&lut[(size_t)c * FEAT + k0 + 4 * k4];
        } else {
          v = *(const float4*)&cq[(size_t)(c - LUT_PAD) * FEAT + k0 + 4 * k4];
        }
        int sw = ((col >> 3) & 7) << 2;
        *(float4*)&xs[col * 68 + ((4 * k4) ^ sw)] = v;
      }
      __syncthreads();
      const int sw = (tc & 7) << 2;
#pragma unroll 2
      for (int kk = 0; kk < 64; kk += 4) {
        float4 qv[4], xv[8];
#pragma unroll
        for (int i = 0; i < 4; ++i) qv[i] = *(const float4*)&qs[(r0 + i) * 68 + kk];
#pragma unroll
        for (int j = 0; j < 8; ++j) xv[j] = *(const float4*)&xs[(c0 + j) * 68 + (kk ^ sw)];
#pragma unroll
        for (int i = 0; i < 4; ++i)
#pragma unroll
          for (int j = 0; j < 8; ++j)
            acc[i][j] += qv[i].x * xv[j].x + qv[i].y * xv[j].y +
                         qv[i].z * xv[j].z + qv[i].w * xv[j].w;
      }
      __syncthreads();
    }
    // epilogue: branchless fixed-max sumexp (|z| <= 30 guaranteed)
#pragma unroll
    for (int j = 0; j < 8; ++j) {
      float2 rc = rn2[colbase + c0 + j];
#pragma unroll
      for (int i = 0; i < 4; ++i) {
        float z = SCALARV * rc.x * (acc[i][j] + (islut ? cb1[i] : cb2[i]));
        z = fminf(z, rc.y);
        s[i] += __expf(z - SCALARV);
      }
    }
  }
  // reduce across the 16 tc threads sharing each row (reuse xs)
  float* red = xs;
  __syncthreads();
#pragma unroll
  for (int i = 0; i < 4; ++i) red[(r0 + i) * 16 + tc] = s[i];
  __syncthreads();
  if (tid < 64) {
    float ss = 0.f;
    for (int x = 0; x < 16; ++x) ss += red[tid * 16 + x];
    ws[WS_PART + (size_t)(rowbase + tid) * SLICES + slice] = ss;
  }
}

// ---------------- per-row target logit --------------------------------------
__global__ __launch_bounds__(256) void k_target(const int* __restrict__ label,
                                                const float* __restrict__ lut,
                                                float* __restrict__ ws) {
  const int r = blockIdx.x, t = threadIdx.x;
  const int* flags = (const int*)(ws + WS_FLAGS);
  const float2* rn2 = (const float2*)(ws + WS_RN2);
  int y = label[r];
  if (y >= NUM_PIDS) { if (t == 0) ws[WS_ZT + r] = 0.f; return; }
  if (flags[y] == 1) { if (t == 0) ws[WS_ZT + r] = SCALARV; return; }
  float x = ws[WS_Q1 + (size_t)r * FEAT + t] * lut[(size_t)y * FEAT + t];
  for (int o = 32; o; o >>= 1) x += __shfl_down(x, o);
  __shared__ float w4[4];
  if ((t & 63) == 0) w4[t >> 6] = x;
  __syncthreads();
  if (t == 0) {
    float dot = w4[0] + w4[1] + w4[2] + w4[3];
    ws[WS_ZT + r] = SCALARV * rn2[y].x * (dot + ws[WS_CB1 + r]);
  }
}

// ---------------- merge partials -> loss ------------------------------------
__global__ __launch_bounds__(256) void k_loss(const int* __restrict__ label,
                                              float* __restrict__ ws,
                                              float* __restrict__ out) {
  const int t = threadIdx.x;
  const int* flags = (const int*)(ws + WS_FLAGS);
  float ls = 0.f;
  for (int r = t; r < BATCH; r += 256) {
    int y = label[r];
    if (y >= NUM_PIDS) continue;
    float ss = 0.f;
    for (int sI = 0; sI < SLICES; ++sI) ss += ws[WS_PART + (size_t)r * SLICES + sI];
    if (flags[y] == 1) {   // bad target column: streamed as -30, actual +30
      ss += 1.0f - __expf(-2.0f * SCALARV);
    }
    ls += (SCALARV + __logf(ss)) - ws[WS_ZT + r];
  }
  for (int o = 32; o; o >>= 1) ls += __shfl_down(ls, o);
  __shared__ float w4[4];
  if ((t & 63) == 0) w4[t >> 6] = ls;
  __syncthreads();
  if (t == 0) out[0] = (w4[0] + w4[1] + w4[2] + w4[3]) / (float)BATCH;
}

// ---------------- serial-semantics momentum scatter into lut ----------------
__global__ __launch_bounds__(256) void k_lutupd(const int* __restrict__ label,
                                                const float* __restrict__ inp,
                                                const float* __restrict__ lut,
                                                float* __restrict__ out_lut) {
  const int r = blockIdx.x, t = threadIdx.x;
  int y = label[r];
  if (y >= NUM_PIDS) return;
  __shared__ int lbl[BATCH];
  for (int i = t; i < BATCH; i += 256) lbl[i] = label[i];
  __syncthreads();
  for (int rr = r + 1; rr < BATCH; ++rr) if (lbl[rr] == y) return;  // only last occ. writes
  float f = lut[(size_t)y * FEAT + t];
  for (int rr = 0; rr <= r; ++rr)
    if (lbl[rr] == y) f = 0.5f * f + 0.5f * inp[(size_t)rr * FEAT + t];
  out_lut[(size_t)y * FEAT + t] = f;
}

// ---------------- circular-buffer enqueue into cq ---------------------------
__global__ __launch_bounds__(256) void k_cqupd(const int* __restrict__ label,
                                               const float* __restrict__ inp,
                                               float* __restrict__ out_cq) {
  const int r = blockIdx.x, t = threadIdx.x;
  int y = label[r];
  if (y != NUM_PIDS) return;
  __shared__ int lbl[BATCH];
  for (int i = t; i < BATCH; i += 256) lbl[i] = label[i];
  __syncthreads();
  int rank = 0;
  for (int rr = 0; rr < r; ++rr) rank += (lbl[rr] == NUM_PIDS);
  out_cq[(size_t)rank * FEAT + t] = inp[(size_t)r * FEAT + t];   // <=2048 < 8192, no wrap
}

extern "C" void kernel_launch(void* const* d_in, const int* in_sizes, int n_in,
                              void* d_out, int out_size, void* d_ws, size_t ws_size,
                              hipStream_t stream) {
  const float* inp = (const float*)d_in[0];
  const int* label = (const int*)d_in[1];
  const float* lut = (const float*)d_in[2];
  const float* cq  = (const float*)d_in[3];
  const float* bnw = (const float*)d_in[4];
  const float* bnb = (const float*)d_in[5];
  float* out = (float*)d_out;
  float* ws  = (float*)d_ws;
  int* flags = (int*)(ws + WS_FLAGS);

  float* out_lut = out + 1;
  float* out_cq  = out + 1 + (size_t)NUM_PIDS * FEAT;

  hipMemcpyAsync(out_lut, lut, (size_t)NUM_PIDS * FEAT * sizeof(float),
                 hipMemcpyDeviceToDevice, stream);
  hipMemcpyAsync(out_cq, cq, (size_t)CQ_SIZE * FEAT * sizeof(float),
                 hipMemcpyDeviceToDevice, stream);

  k_stats1<<<NB1, 256, 0, stream>>>(lut, ws, flags);
  k_stats2<<<1, 256, 0, stream>>>(bnw, bnb, ws);
  k_qn<<<BATCH, 256, 0, stream>>>(inp, bnw, bnb, ws);
  k_norms<<<NUM_PIDS + CQ_SIZE, 256, 0, stream>>>(lut, cq, ws);
  k_gemm<<<dim3(SLICES, BATCH / BR), 256, 0, stream>>>(lut, cq, ws);
  k_target<<<BATCH, 256, 0, stream>>>(label, lut, ws);
  k_loss<<<1, 256, 0, stream>>>(label, ws, out);
  k_lutupd<<<BATCH, 256, 0, stream>>>(label, inp, lut, out_lut);
  k_cqupd<<<BATCH, 256, 0, stream>>>(label, inp, out_cq);
}

// Round 4
// 593.542 us; speedup vs baseline: 2.2439x; 2.2439x over previous
//
#include <hip/hip_runtime.h>
#include <math.h>

#define NUM_PIDS 30000
#define CQ_SIZE  8192
#define BATCH    2048
#define FEAT     256
#define EPS_BN   1e-5f
#define EPS_NORM 1e-12f
#define SCALARV  30.0f

// padded column space: [0,30000) lut, [30000,30080) pad, [30080,38272) cq
#define LUT_PAD  30080
#define NCOL     38272
#define BC       128
#define LUT_TILES 235     // 30080/128
#define CT       299      // 235 lut tiles + 64 cq tiles
#define RT       16       // 2048/128 row tiles
#define NWG      (CT*RT)  // 4784 = 8*598 (XCD-divisible)
#define NB1      120      // stats blocks, 250 lut rows each
#define QPLANE   (BATCH*FEAT)   // ushorts per q plane

// workspace layout (float element offsets)
#define WS_Q1    0
#define WS_CB1   (WS_Q1 + BATCH*FEAT)
#define WS_CB2   (WS_CB1 + BATCH)
#define WS_RN2   (WS_CB2 + BATCH)          // float2 per column: {rn, cap}
#define WS_FLAGS (WS_RN2 + 2*NCOL)         // int32, lut rows only
#define WS_PSUM  (WS_FLAGS + LUT_PAD)
#define WS_PSQ   (WS_PSUM + NB1*FEAT)
#define WS_PCNT  (WS_PSQ + NB1*FEAT)
#define WS_A1    (WS_PCNT + 128)
#define WS_B1    (WS_A1 + FEAT)
#define WS_A2    (WS_B1 + FEAT)
#define WS_B2    (WS_A2 + FEAT)
#define WS_ZT    (WS_B2 + FEAT)
#define WS_PART  (WS_ZT + BATCH)           // BATCH*CT floats
#define WS_LOSS8 (WS_PART + BATCH*CT)
#define WS_XH    ((WS_LOSS8 + 8 + 3) & ~3) // 16B-aligned; ushort plane
#define WS_XL    (WS_XH + NCOL*FEAT/2)
#define WS_QP    (WS_XL + NCOL*FEAT/2)     // 4 planes: q1h,q1l,q2h,q2l

typedef __bf16 bf16x8 __attribute__((ext_vector_type(8)));
typedef float  f32x4  __attribute__((ext_vector_type(4)));

__device__ __forceinline__ unsigned short f2bf(float f) {
  __bf16 h = (__bf16)f; return __builtin_bit_cast(unsigned short, h);
}
__device__ __forceinline__ float bf2f(unsigned short u) {
  __bf16 h = __builtin_bit_cast(__bf16, u); return (float)h;
}
__device__ __forceinline__ void gload_lds16(const void* g, void* l) {
  __builtin_amdgcn_global_load_lds((__attribute__((address_space(1))) void*)(g),
                                   (__attribute__((address_space(3))) void*)(l), 16, 0, 0);
}

// ---------------- stats pass 1 (single-pass: zero rows contribute 0) --------
__global__ __launch_bounds__(256) void k_stats1(const float* __restrict__ lut,
                                                float* __restrict__ ws,
                                                int* __restrict__ flags) {
  const int t = threadIdx.x;
  const int rbase = blockIdx.x * 250;
  __shared__ unsigned char wz[250 * 4];
  float s = 0.f, sq = 0.f;
  for (int i = 0; i < 250; ++i) {
    float v = lut[(size_t)(rbase + i) * FEAT + t];
    s += v; sq += v * v;                       // bad rows are all-zero: add 0
    unsigned long long bal = __ballot(v != 0.0f);
    if ((t & 63) == 0) wz[i * 4 + (t >> 6)] = (bal != 0ull) ? 1 : 0;
  }
  __syncthreads();
  for (int i = t; i < 250; i += 256) {
    int bad = !(wz[i*4] | wz[i*4+1] | wz[i*4+2] | wz[i*4+3]);
    flags[rbase + i] = bad;
  }
  ws[WS_PSUM + blockIdx.x * FEAT + t] = s;
  ws[WS_PSQ  + blockIdx.x * FEAT + t] = sq;
  if (t == 0) {
    int cnt = 0;
    for (int i = 0; i < 250; ++i)
      cnt += (wz[i*4] | wz[i*4+1] | wz[i*4+2] | wz[i*4+3]) ? 1 : 0;
    ws[WS_PCNT + blockIdx.x] = (float)cnt;
  }
}

// ---------------- stats pass 2 ----------------------------------------------
__global__ __launch_bounds__(256) void k_stats2(const float* __restrict__ bnw,
                                                const float* __restrict__ bnb,
                                                float* __restrict__ ws) {
  const int t = threadIdx.x;
  float2* rn2 = (float2*)(ws + WS_RN2);
  float s = 0.f, sq = 0.f, n = 0.f;
  for (int b = 0; b < NB1; ++b) { s += ws[WS_PSUM + b*FEAT + t]; sq += ws[WS_PSQ + b*FEAT + t]; }
  for (int b = 0; b < NB1; ++b) n += ws[WS_PCNT + b];
  float mean = s / n;
  float var = fmaxf(sq / n - mean * mean, 0.f);
  float istd_b = rsqrtf(var + EPS_BN);
  float rv1 = var * n / (n - 1.f);
  float istd_u = rsqrtf(rv1 + EPS_BN);
  float w = bnw[t], b_ = bnb[t];
  float a1 = istd_b * w, a2 = istd_u * w;
  ws[WS_A1 + t] = a1; ws[WS_B1 + t] = b_ - mean * a1;
  ws[WS_A2 + t] = a2; ws[WS_B2 + t] = b_ - mean * a2;
  if (t < (LUT_PAD - NUM_PIDS)) rn2[NUM_PIDS + t] = make_float2(0.f, -1e30f);
}

// ---------------- raw X -> bf16 hi/lo planes (incl. zero pads) --------------
__global__ __launch_bounds__(256) void k_split(const float* __restrict__ lut,
                                               const float* __restrict__ cq,
                                               unsigned short* __restrict__ xh,
                                               unsigned short* __restrict__ xl) {
  const int stride = gridDim.x * blockDim.x;
  for (int u = blockIdx.x * blockDim.x + threadIdx.x; u < NCOL * 32; u += stride) {
    int col = u >> 5, k8 = (u & 31) * 8;
    float v[8];
    if (col < NUM_PIDS) {
      const float4* p = (const float4*)&lut[(size_t)col * FEAT + k8];
      float4 a = p[0], b = p[1];
      v[0]=a.x; v[1]=a.y; v[2]=a.z; v[3]=a.w; v[4]=b.x; v[5]=b.y; v[6]=b.z; v[7]=b.w;
    } else if (col < LUT_PAD) {
#pragma unroll
      for (int j = 0; j < 8; ++j) v[j] = 0.f;
    } else {
      const float4* p = (const float4*)&cq[(size_t)(col - LUT_PAD) * FEAT + k8];
      float4 a = p[0], b = p[1];
      v[0]=a.x; v[1]=a.y; v[2]=a.z; v[3]=a.w; v[4]=b.x; v[5]=b.y; v[6]=b.z; v[7]=b.w;
    }
    unsigned int hp[4], lp[4];
#pragma unroll
    for (int j = 0; j < 4; ++j) {
      unsigned short h0 = f2bf(v[2*j]),   h1 = f2bf(v[2*j+1]);
      unsigned short l0 = f2bf(v[2*j]   - bf2f(h0));
      unsigned short l1 = f2bf(v[2*j+1] - bf2f(h1));
      hp[j] = (unsigned int)h0 | ((unsigned int)h1 << 16);
      lp[j] = (unsigned int)l0 | ((unsigned int)l1 << 16);
    }
    size_t off = (size_t)col * FEAT + k8;
    *(uint4*)(xh + off) = make_uint4(hp[0], hp[1], hp[2], hp[3]);
    *(uint4*)(xl + off) = make_uint4(lp[0], lp[1], lp[2], lp[3]);
  }
}

// ---------------- qn + q1/q2 planes + per-row scalars -----------------------
__global__ __launch_bounds__(256) void k_qn(const float* __restrict__ inp,
                                            const float* __restrict__ bnw,
                                            const float* __restrict__ bnb,
                                            float* __restrict__ ws,
                                            unsigned short* __restrict__ qp) {
  const int r = blockIdx.x, t = threadIdx.x;
  const float s0 = rsqrtf(1.0f + EPS_BN);
  float v = inp[(size_t)r * FEAT + t];
  float bn = v * (bnw[t] * s0) + bnb[t];
  float x = bn * bn;
  for (int o = 32; o; o >>= 1) x += __shfl_down(x, o);
  __shared__ float w4[4];
  __shared__ float w8[8];
  if ((t & 63) == 0) w4[t >> 6] = x;
  __syncthreads();
  float nsq = w4[0] + w4[1] + w4[2] + w4[3];
  float rinv = 1.0f / fmaxf(sqrtf(nsq), EPS_NORM);
  float qn = bn * rinv;
  float y1 = qn * ws[WS_B1 + t], y2 = qn * ws[WS_B2 + t];
  for (int o = 32; o; o >>= 1) { y1 += __shfl_down(y1, o); y2 += __shfl_down(y2, o); }
  if ((t & 63) == 0) { w8[t >> 6] = y1; w8[4 + (t >> 6)] = y2; }
  float q1 = qn * ws[WS_A1 + t], q2 = qn * ws[WS_A2 + t];
  ws[WS_Q1 + (size_t)r * FEAT + t] = q1;
  size_t o1 = (size_t)r * FEAT + t;
  unsigned short h1 = f2bf(q1), h2 = f2bf(q2);
  qp[0*QPLANE + o1] = h1;
  qp[1*QPLANE + o1] = f2bf(q1 - bf2f(h1));
  qp[2*QPLANE + o1] = h2;
  qp[3*QPLANE + o1] = f2bf(q2 - bf2f(h2));
  __syncthreads();
  if (t == 0) {
    ws[WS_CB1 + r] = w8[0] + w8[1] + w8[2] + w8[3];
    ws[WS_CB2 + r] = w8[4] + w8[5] + w8[6] + w8[7];
  }
}

// ---------------- per-column {rn, cap} --------------------------------------
__global__ __launch_bounds__(256) void k_norms(const float* __restrict__ lut,
                                               const float* __restrict__ cq,
                                               float* __restrict__ ws) {
  const int t = threadIdx.x;
  const int row = blockIdx.x;  // 0..38191
  float2* rn2 = (float2*)(ws + WS_RN2);
  const int* flags = (const int*)(ws + WS_FLAGS);
  float a, b, v; int cidx, bad;
  __shared__ unsigned char wzs[4];
  __shared__ float w4[4];
  if (row < NUM_PIDS) {
    v = lut[(size_t)row * FEAT + t];
    a = ws[WS_A1 + t]; b = ws[WS_B1 + t];
    cidx = row;
    bad = flags[row];
  } else {
    int q = row - NUM_PIDS;
    v = cq[(size_t)q * FEAT + t];
    a = ws[WS_A2 + t]; b = ws[WS_B2 + t];
    cidx = LUT_PAD + q;
    unsigned long long bal = __ballot(v != 0.0f);
    if ((t & 63) == 0) wzs[t >> 6] = (bal != 0ull) ? 1 : 0;
    __syncthreads();
    bad = !(wzs[0] | wzs[1] | wzs[2] | wzs[3]);
  }
  float bn = bad ? 0.f : (v * a + b);
  float x = bn * bn;
  for (int o = 32; o; o >>= 1) x += __shfl_down(x, o);
  if ((t & 63) == 0) w4[t >> 6] = x;
  __syncthreads();
  if (t == 0) {
    float nrm = sqrtf(w4[0] + w4[1] + w4[2] + w4[3]);
    // bad column: raw row all-zero -> acc=0; rn=0 gives z=0, cap=-30 -> exact -30 logit
    rn2[cidx] = bad ? make_float2(0.f, -SCALARV)
                    : make_float2(1.0f / fmaxf(nrm, EPS_NORM), 1e30f);
  }
}

// ---------------- MFMA GEMM (bf16 hi/lo split) + fixed-max(30) sumexp -------
__global__ __launch_bounds__(256) void k_gemm(const unsigned short* __restrict__ xh,
                                              const unsigned short* __restrict__ xl,
                                              const unsigned short* __restrict__ qp,
                                              float* __restrict__ ws) {
  __shared__ __align__(16) unsigned char smem[65536];  // XH|XL|QH|QL 16KB each
  const int tid = threadIdx.x;
  const int w = tid >> 6, l = tid & 63;
  // bijective XCD chunk swizzle (4784 = 8*598)
  const int bid = blockIdx.x;
  const int sid = (bid & 7) * (NWG / 8) + (bid >> 3);
  const int colT = sid >> 4, rowT = sid & 15;
  const bool islut = colT < LUT_TILES;
  const int colbase = colT * BC;
  const int rowbase = rowT * 128;

  const unsigned short* qh = qp + (islut ? 0 : 2) * QPLANE;
  const unsigned short* ql = qh + QPLANE;

  // staging geometry: lane l -> row 8i+(l>>3); LDS slot (l&7) holds k-chunk (l&7)^(l>>3)
  const int segc = l >> 3, slot = l & 7;
  const int kc8l = slot ^ segc;
  const unsigned short* gsrc;
  unsigned char* lbase;
  int gbase;
  if (w == 0)      { gsrc = xh; lbase = smem;         gbase = colbase; }
  else if (w == 1) { gsrc = xl; lbase = smem + 16384; gbase = colbase; }
  else if (w == 2) { gsrc = qh; lbase = smem + 32768; gbase = rowbase; }
  else             { gsrc = ql; lbase = smem + 49152; gbase = rowbase; }

  const int lc = l & 15, lk = l >> 4;
  const int wr = w >> 1, wc = w & 1;

  f32x4 acc[4][4];
#pragma unroll
  for (int rf = 0; rf < 4; ++rf)
#pragma unroll
    for (int cf = 0; cf < 4; ++cf) { f32x4 z = {0.f,0.f,0.f,0.f}; acc[rf][cf] = z; }

  for (int kc = 0; kc < 4; ++kc) {
    const int kb = kc * 64;
#pragma unroll
    for (int i = 0; i < 16; ++i) {
      const unsigned short* g = gsrc + (size_t)(gbase + i * 8 + segc) * FEAT + kb + kc8l * 8;
      gload_lds16(g, lbase + i * 1024);
    }
    __syncthreads();
#pragma unroll
    for (int ks = 0; ks < 2; ++ks) {
      const int kc8 = ks * 4 + lk;
      const int sA = (kc8 ^ (lc & 7)) * 16;
      bf16x8 ah[4], al[4], bh[4], bl[4];
#pragma unroll
      for (int rf = 0; rf < 4; ++rf) {
        int off = (wr * 64 + rf * 16 + lc) * 128 + sA;
        ah[rf] = *(const bf16x8*)(smem + 32768 + off);
        al[rf] = *(const bf16x8*)(smem + 49152 + off);
      }
#pragma unroll
      for (int cf = 0; cf < 4; ++cf) {
        int off = (wc * 64 + cf * 16 + lc) * 128 + sA;
        bh[cf] = *(const bf16x8*)(smem + off);
        bl[cf] = *(const bf16x8*)(smem + 16384 + off);
      }
#pragma unroll
      for (int rf = 0; rf < 4; ++rf)
#pragma unroll
        for (int cf = 0; cf < 4; ++cf) {
          acc[rf][cf] = __builtin_amdgcn_mfma_f32_16x16x32_bf16(ah[rf], bh[cf], acc[rf][cf], 0, 0, 0);
          acc[rf][cf] = __builtin_amdgcn_mfma_f32_16x16x32_bf16(ah[rf], bl[cf], acc[rf][cf], 0, 0, 0);
          acc[rf][cf] = __builtin_amdgcn_mfma_f32_16x16x32_bf16(al[rf], bh[cf], acc[rf][cf], 0, 0, 0);
        }
    }
    __syncthreads();
  }

  // epilogue: z = min(30*rn*(acc+cb), cap); sum exp(z-30) over this tile's cols
  const float* cb = ws + (islut ? WS_CB1 : WS_CB2);
  const float2* rn2 = (const float2*)(ws + WS_RN2);
  float* red = (float*)smem;   // [128][2]
#pragma unroll
  for (int rf = 0; rf < 4; ++rf) {
    float cbv[4];
#pragma unroll
    for (int r4 = 0; r4 < 4; ++r4)
      cbv[r4] = cb[rowbase + wr * 64 + rf * 16 + lk * 4 + r4];
    float part[4] = {0.f, 0.f, 0.f, 0.f};
#pragma unroll
    for (int cf = 0; cf < 4; ++cf) {
      float2 rc = rn2[colbase + wc * 64 + cf * 16 + lc];
#pragma unroll
      for (int r4 = 0; r4 < 4; ++r4) {
        float z = SCALARV * rc.x * (acc[rf][cf][r4] + cbv[r4]);
        z = fminf(z, rc.y);
        part[r4] += __expf(z - SCALARV);
      }
    }
#pragma unroll
    for (int r4 = 0; r4 < 4; ++r4) {
#pragma unroll
      for (int o = 1; o < 16; o <<= 1) part[r4] += __shfl_xor(part[r4], o);
      if (lc == 0) red[(wr * 64 + rf * 16 + lk * 4 + r4) * 2 + wc] = part[r4];
    }
  }
  __syncthreads();
  if (tid < 128) {
    float val = red[tid * 2] + red[tid * 2 + 1];
    ws[WS_PART + (size_t)(rowbase + tid) * CT + colT] = val;
  }
}

// ---------------- per-row target logit --------------------------------------
__global__ __launch_bounds__(256) void k_target(const int* __restrict__ label,
                                                const float* __restrict__ lut,
                                                float* __restrict__ ws) {
  const int r = blockIdx.x, t = threadIdx.x;
  const int* flags = (const int*)(ws + WS_FLAGS);
  const float2* rn2 = (const float2*)(ws + WS_RN2);
  int y = label[r];
  if (y >= NUM_PIDS) { if (t == 0) ws[WS_ZT + r] = 0.f; return; }
  if (flags[y] == 1) { if (t == 0) ws[WS_ZT + r] = SCALARV; return; }
  float x = ws[WS_Q1 + (size_t)r * FEAT + t] * lut[(size_t)y * FEAT + t];
  for (int o = 32; o; o >>= 1) x += __shfl_down(x, o);
  __shared__ float w4[4];
  if ((t & 63) == 0) w4[t >> 6] = x;
  __syncthreads();
  if (t == 0) {
    float dot = w4[0] + w4[1] + w4[2] + w4[3];
    ws[WS_ZT + r] = SCALARV * rn2[y].x * (dot + ws[WS_CB1 + r]);
  }
}

// ---------------- merge partials -> per-block loss sums ---------------------
__global__ __launch_bounds__(256) void k_loss(const int* __restrict__ label,
                                              float* __restrict__ ws) {
  const int t = threadIdx.x;
  const int r = blockIdx.x * 256 + t;
  const int* flags = (const int*)(ws + WS_FLAGS);
  float ls = 0.f;
  int y = label[r];
  if (y < NUM_PIDS) {
    float ss = 0.f;
    const float* p = ws + WS_PART + (size_t)r * CT;
    for (int c = 0; c < CT; ++c) ss += p[c];
    if (flags[y] == 1) ss += 1.0f - __expf(-2.0f * SCALARV);
    ls = (SCALARV + __logf(ss)) - ws[WS_ZT + r];
  }
  for (int o = 32; o; o >>= 1) ls += __shfl_down(ls, o);
  __shared__ float w4[4];
  if ((t & 63) == 0) w4[t >> 6] = ls;
  __syncthreads();
  if (t == 0) ws[WS_LOSS8 + blockIdx.x] = w4[0] + w4[1] + w4[2] + w4[3];
}

__global__ void k_loss2(float* __restrict__ ws, float* __restrict__ out) {
  if (threadIdx.x == 0) {
    float s = 0.f;
    for (int i = 0; i < 8; ++i) s += ws[WS_LOSS8 + i];
    out[0] = s / (float)BATCH;
  }
}

// ---------------- serial-semantics momentum scatter into lut ----------------
__global__ __launch_bounds__(256) void k_lutupd(const int* __restrict__ label,
                                                const float* __restrict__ inp,
                                                const float* __restrict__ lut,
                                                float* __restrict__ out_lut) {
  const int r = blockIdx.x, t = threadIdx.x;
  int y = label[r];
  if (y >= NUM_PIDS) return;
  __shared__ int lbl[BATCH];
  for (int i = t; i < BATCH; i += 256) lbl[i] = label[i];
  __syncthreads();
  for (int rr = r + 1; rr < BATCH; ++rr) if (lbl[rr] == y) return;  // only last occ. writes
  float f = lut[(size_t)y * FEAT + t];
  for (int rr = 0; rr <= r; ++rr)
    if (lbl[rr] == y) f = 0.5f * f + 0.5f * inp[(size_t)rr * FEAT + t];
  out_lut[(size_t)y * FEAT + t] = f;
}

// ---------------- circular-buffer enqueue into cq ---------------------------
__global__ __launch_bounds__(256) void k_cqupd(const int* __restrict__ label,
                                               const float* __restrict__ inp,
                                               float* __restrict__ out_cq) {
  const int r = blockIdx.x, t = threadIdx.x;
  int y = label[r];
  if (y != NUM_PIDS) return;
  __shared__ int lbl[BATCH];
  for (int i = t; i < BATCH; i += 256) lbl[i] = label[i];
  __syncthreads();
  int rank = 0;
  for (int rr = 0; rr < r; ++rr) rank += (lbl[rr] == NUM_PIDS);
  out_cq[(size_t)rank * FEAT + t] = inp[(size_t)r * FEAT + t];   // <=2048 < 8192, no wrap
}

extern "C" void kernel_launch(void* const* d_in, const int* in_sizes, int n_in,
                              void* d_out, int out_size, void* d_ws, size_t ws_size,
                              hipStream_t stream) {
  const float* inp = (const float*)d_in[0];
  const int* label = (const int*)d_in[1];
  const float* lut = (const float*)d_in[2];
  const float* cq  = (const float*)d_in[3];
  const float* bnw = (const float*)d_in[4];
  const float* bnb = (const float*)d_in[5];
  float* out = (float*)d_out;
  float* ws  = (float*)d_ws;
  int* flags = (int*)(ws + WS_FLAGS);
  unsigned short* xh = (unsigned short*)(ws + WS_XH);
  unsigned short* xl = (unsigned short*)(ws + WS_XL);
  unsigned short* qp = (unsigned short*)(ws + WS_QP);

  float* out_lut = out + 1;
  float* out_cq  = out + 1 + (size_t)NUM_PIDS * FEAT;

  hipMemcpyAsync(out_lut, lut, (size_t)NUM_PIDS * FEAT * sizeof(float),
                 hipMemcpyDeviceToDevice, stream);
  hipMemcpyAsync(out_cq, cq, (size_t)CQ_SIZE * FEAT * sizeof(float),
                 hipMemcpyDeviceToDevice, stream);

  k_split<<<2048, 256, 0, stream>>>(lut, cq, xh, xl);
  k_stats1<<<NB1, 256, 0, stream>>>(lut, ws, flags);
  k_stats2<<<1, 256, 0, stream>>>(bnw, bnb, ws);
  k_qn<<<BATCH, 256, 0, stream>>>(inp, bnw, bnb, ws, qp);
  k_norms<<<NUM_PIDS + CQ_SIZE, 256, 0, stream>>>(lut, cq, ws);
  k_gemm<<<NWG, 256, 0, stream>>>(xh, xl, qp, ws);
  k_target<<<BATCH, 256, 0, stream>>>(label, lut, ws);
  k_loss<<<8, 256, 0, stream>>>(label, ws);
  k_loss2<<<1, 64, 0, stream>>>(ws, out);
  k_lutupd<<<BATCH, 256, 0, stream>>>(label, inp, lut, out_lut);
  k_cqupd<<<BATCH, 256, 0, stream>>>(label, inp, out_cq);
}

// Round 6
// 390.762 us; speedup vs baseline: 3.4083x; 1.5189x over previous
//
#include <hip/hip_runtime.h>
#include <math.h>

#define NUM_PIDS 30000
#define CQ_SIZE  8192
#define BATCH    2048
#define FEAT     256
#define EPS_BN   1e-5f
#define EPS_NORM 1e-12f
#define SCALARV  30.0f

// padded column space: [0,30000) lut, [30000,30080) pad, [30080,38272) cq
#define LUT_PAD  30080
#define NCOL     38272
#define BC       128
#define LUT_TILES 235     // 30080/128
#define CT       299      // 235 lut tiles + 64 cq tiles
#define RT       16       // 2048/128 row tiles
#define NWG      (CT*RT)  // 4784 = 8*598 (XCD-divisible)
#define NB1      120      // stats blocks, 250 lut rows each
#define QPLANE   (BATCH*FEAT)   // ushorts per q plane

// workspace layout (float element offsets)
#define WS_Q1    0
#define WS_CB1   (WS_Q1 + BATCH*FEAT)
#define WS_CB2   (WS_CB1 + BATCH)
#define WS_RN2   (WS_CB2 + BATCH)          // float2 per column: {rn, cap}
#define WS_FLAGS (WS_RN2 + 2*NCOL)         // int32, lut rows only
#define WS_PSUM  (WS_FLAGS + LUT_PAD)
#define WS_PSQ   (WS_PSUM + NB1*FEAT)
#define WS_PCNT  (WS_PSQ + NB1*FEAT)
#define WS_A1    (WS_PCNT + 128)
#define WS_B1    (WS_A1 + FEAT)
#define WS_A2    (WS_B1 + FEAT)
#define WS_B2    (WS_A2 + FEAT)
#define WS_ZT    (WS_B2 + FEAT)
#define WS_PART  (WS_ZT + BATCH)           // BATCH*CT floats
#define WS_LOSS8 (WS_PART + BATCH*CT)
#define WS_XH    ((WS_LOSS8 + 8 + 3) & ~3) // 16B-aligned; ushort plane
#define WS_XL    (WS_XH + NCOL*FEAT/2)
#define WS_QP    (WS_XL + NCOL*FEAT/2)     // 4 planes: q1h,q1l,q2h,q2l

typedef __bf16 bf16x8 __attribute__((ext_vector_type(8)));
typedef float  f32x4  __attribute__((ext_vector_type(4)));

__device__ __forceinline__ unsigned short f2bf(float f) {
  __bf16 h = (__bf16)f; return __builtin_bit_cast(unsigned short, h);
}
__device__ __forceinline__ float bf2f(unsigned short u) {
  __bf16 h = __builtin_bit_cast(__bf16, u); return (float)h;
}
__device__ __forceinline__ void gload_lds16(const void* g, void* l) {
  __builtin_amdgcn_global_load_lds((__attribute__((address_space(1))) void*)(g),
                                   (__attribute__((address_space(3))) void*)(l), 16, 0, 0);
}

// ---------------- stats pass 1 (single-pass: zero rows contribute 0) --------
__global__ __launch_bounds__(256) void k_stats1(const float* __restrict__ lut,
                                                float* __restrict__ ws,
                                                int* __restrict__ flags) {
  const int t = threadIdx.x;
  const int rbase = blockIdx.x * 250;
  __shared__ unsigned char wz[250 * 4];
  float s = 0.f, sq = 0.f;
  for (int i = 0; i < 250; ++i) {
    float v = lut[(size_t)(rbase + i) * FEAT + t];
    s += v; sq += v * v;                       // bad rows are all-zero: add 0
    unsigned long long bal = __ballot(v != 0.0f);
    if ((t & 63) == 0) wz[i * 4 + (t >> 6)] = (bal != 0ull) ? 1 : 0;
  }
  __syncthreads();
  for (int i = t; i < 250; i += 256) {
    int bad = !(wz[i*4] | wz[i*4+1] | wz[i*4+2] | wz[i*4+3]);
    flags[rbase + i] = bad;
  }
  ws[WS_PSUM + blockIdx.x * FEAT + t] = s;
  ws[WS_PSQ  + blockIdx.x * FEAT + t] = sq;
  if (t == 0) {
    int cnt = 0;
    for (int i = 0; i < 250; ++i)
      cnt += (wz[i*4] | wz[i*4+1] | wz[i*4+2] | wz[i*4+3]) ? 1 : 0;
    ws[WS_PCNT + blockIdx.x] = (float)cnt;
  }
}

// ---------------- stats pass 2 ----------------------------------------------
__global__ __launch_bounds__(256) void k_stats2(const float* __restrict__ bnw,
                                                const float* __restrict__ bnb,
                                                float* __restrict__ ws) {
  const int t = threadIdx.x;
  float2* rn2 = (float2*)(ws + WS_RN2);
  float s = 0.f, sq = 0.f, n = 0.f;
  for (int b = 0; b < NB1; ++b) { s += ws[WS_PSUM + b*FEAT + t]; sq += ws[WS_PSQ + b*FEAT + t]; }
  for (int b = 0; b < NB1; ++b) n += ws[WS_PCNT + b];
  float mean = s / n;
  float var = fmaxf(sq / n - mean * mean, 0.f);
  float istd_b = rsqrtf(var + EPS_BN);
  float rv1 = var * n / (n - 1.f);
  float istd_u = rsqrtf(rv1 + EPS_BN);
  float w = bnw[t], b_ = bnb[t];
  float a1 = istd_b * w, a2 = istd_u * w;
  ws[WS_A1 + t] = a1; ws[WS_B1 + t] = b_ - mean * a1;
  ws[WS_A2 + t] = a2; ws[WS_B2 + t] = b_ - mean * a2;
  if (t < (LUT_PAD - NUM_PIDS)) rn2[NUM_PIDS + t] = make_float2(0.f, -1e30f);
}

// ---------------- raw X -> bf16 hi/lo planes (incl. zero pads) --------------
__global__ __launch_bounds__(256) void k_split(const float* __restrict__ lut,
                                               const float* __restrict__ cq,
                                               unsigned short* __restrict__ xh,
                                               unsigned short* __restrict__ xl) {
  const int stride = gridDim.x * blockDim.x;
  for (int u = blockIdx.x * blockDim.x + threadIdx.x; u < NCOL * 32; u += stride) {
    int col = u >> 5, k8 = (u & 31) * 8;
    float v[8];
    if (col < NUM_PIDS) {
      const float4* p = (const float4*)&lut[(size_t)col * FEAT + k8];
      float4 a = p[0], b = p[1];
      v[0]=a.x; v[1]=a.y; v[2]=a.z; v[3]=a.w; v[4]=b.x; v[5]=b.y; v[6]=b.z; v[7]=b.w;
    } else if (col < LUT_PAD) {
#pragma unroll
      for (int j = 0; j < 8; ++j) v[j] = 0.f;
    } else {
      const float4* p = (const float4*)&cq[(size_t)(col - LUT_PAD) * FEAT + k8];
      float4 a = p[0], b = p[1];
      v[0]=a.x; v[1]=a.y; v[2]=a.z; v[3]=a.w; v[4]=b.x; v[5]=b.y; v[6]=b.z; v[7]=b.w;
    }
    unsigned int hp[4], lp[4];
#pragma unroll
    for (int j = 0; j < 4; ++j) {
      unsigned short h0 = f2bf(v[2*j]),   h1 = f2bf(v[2*j+1]);
      unsigned short l0 = f2bf(v[2*j]   - bf2f(h0));
      unsigned short l1 = f2bf(v[2*j+1] - bf2f(h1));
      hp[j] = (unsigned int)h0 | ((unsigned int)h1 << 16);
      lp[j] = (unsigned int)l0 | ((unsigned int)l1 << 16);
    }
    size_t off = (size_t)col * FEAT + k8;
    *(uint4*)(xh + off) = make_uint4(hp[0], hp[1], hp[2], hp[3]);
    *(uint4*)(xl + off) = make_uint4(lp[0], lp[1], lp[2], lp[3]);
  }
}

// ---------------- qn + q1/q2 planes + per-row scalars -----------------------
__global__ __launch_bounds__(256) void k_qn(const float* __restrict__ inp,
                                            const float* __restrict__ bnw,
                                            const float* __restrict__ bnb,
                                            float* __restrict__ ws,
                                            unsigned short* __restrict__ qp) {
  const int r = blockIdx.x, t = threadIdx.x;
  const float s0 = rsqrtf(1.0f + EPS_BN);
  float v = inp[(size_t)r * FEAT + t];
  float bn = v * (bnw[t] * s0) + bnb[t];
  float x = bn * bn;
  for (int o = 32; o; o >>= 1) x += __shfl_down(x, o);
  __shared__ float w4[4];
  __shared__ float w8[8];
  if ((t & 63) == 0) w4[t >> 6] = x;
  __syncthreads();
  float nsq = w4[0] + w4[1] + w4[2] + w4[3];
  float rinv = 1.0f / fmaxf(sqrtf(nsq), EPS_NORM);
  float qn = bn * rinv;
  float y1 = qn * ws[WS_B1 + t], y2 = qn * ws[WS_B2 + t];
  for (int o = 32; o; o >>= 1) { y1 += __shfl_down(y1, o); y2 += __shfl_down(y2, o); }
  if ((t & 63) == 0) { w8[t >> 6] = y1; w8[4 + (t >> 6)] = y2; }
  float q1 = qn * ws[WS_A1 + t], q2 = qn * ws[WS_A2 + t];
  ws[WS_Q1 + (size_t)r * FEAT + t] = q1;
  size_t o1 = (size_t)r * FEAT + t;
  unsigned short h1 = f2bf(q1), h2 = f2bf(q2);
  qp[0*QPLANE + o1] = h1;
  qp[1*QPLANE + o1] = f2bf(q1 - bf2f(h1));
  qp[2*QPLANE + o1] = h2;
  qp[3*QPLANE + o1] = f2bf(q2 - bf2f(h2));
  __syncthreads();
  if (t == 0) {
    ws[WS_CB1 + r] = w8[0] + w8[1] + w8[2] + w8[3];
    ws[WS_CB2 + r] = w8[4] + w8[5] + w8[6] + w8[7];
  }
}

// ---------------- per-column {rn, cap} --------------------------------------
__global__ __launch_bounds__(256) void k_norms(const float* __restrict__ lut,
                                               const float* __restrict__ cq,
                                               float* __restrict__ ws) {
  const int t = threadIdx.x;
  const int row = blockIdx.x;  // 0..38191
  float2* rn2 = (float2*)(ws + WS_RN2);
  const int* flags = (const int*)(ws + WS_FLAGS);
  float a, b, v; int cidx, bad;
  __shared__ unsigned char wzs[4];
  __shared__ float w4[4];
  if (row < NUM_PIDS) {
    v = lut[(size_t)row * FEAT + t];
    a = ws[WS_A1 + t]; b = ws[WS_B1 + t];
    cidx = row;
    bad = flags[row];
  } else {
    int q = row - NUM_PIDS;
    v = cq[(size_t)q * FEAT + t];
    a = ws[WS_A2 + t]; b = ws[WS_B2 + t];
    cidx = LUT_PAD + q;
    unsigned long long bal = __ballot(v != 0.0f);
    if ((t & 63) == 0) wzs[t >> 6] = (bal != 0ull) ? 1 : 0;
    __syncthreads();
    bad = !(wzs[0] | wzs[1] | wzs[2] | wzs[3]);
  }
  float bn = bad ? 0.f : (v * a + b);
  float x = bn * bn;
  for (int o = 32; o; o >>= 1) x += __shfl_down(x, o);
  if ((t & 63) == 0) w4[t >> 6] = x;
  __syncthreads();
  if (t == 0) {
    float nrm = sqrtf(w4[0] + w4[1] + w4[2] + w4[3]);
    // bad column: raw row all-zero -> acc=0; rn=0 gives z=0, cap=-30 -> exact -30 logit
    rn2[cidx] = bad ? make_float2(0.f, -SCALARV)
                    : make_float2(1.0f / fmaxf(nrm, EPS_NORM), 1e30f);
  }
}

// ---------------- MFMA GEMM (bf16 hi/lo split) + fixed-max(30) sumexp -------
__global__ __launch_bounds__(256) void k_gemm(const unsigned short* __restrict__ xh,
                                              const unsigned short* __restrict__ xl,
                                              const unsigned short* __restrict__ qp,
                                              float* __restrict__ ws) {
  __shared__ __align__(16) unsigned char smem[65536];  // XH|XL|QH|QL 16KB each
  const int tid = threadIdx.x;
  const int w = tid >> 6, l = tid & 63;
  // bijective XCD chunk swizzle (4784 = 8*598)
  const int bid = blockIdx.x;
  const int sid = (bid & 7) * (NWG / 8) + (bid >> 3);
  const int colT = sid >> 4, rowT = sid & 15;
  const bool islut = colT < LUT_TILES;
  const int colbase = colT * BC;
  const int rowbase = rowT * 128;

  const unsigned short* qh = qp + (islut ? 0 : 2) * QPLANE;
  const unsigned short* ql = qh + QPLANE;

  // staging geometry: lane l -> row 8i+(l>>3); LDS slot (l&7) holds k-chunk (l&7)^(l>>3)
  const int segc = l >> 3, slot = l & 7;
  const int kc8l = slot ^ segc;
  const unsigned short* gsrc;
  unsigned char* lbase;
  int gbase;
  if (w == 0)      { gsrc = xh; lbase = smem;         gbase = colbase; }
  else if (w == 1) { gsrc = xl; lbase = smem + 16384; gbase = colbase; }
  else if (w == 2) { gsrc = qh; lbase = smem + 32768; gbase = rowbase; }
  else             { gsrc = ql; lbase = smem + 49152; gbase = rowbase; }

  const int lc = l & 15, lk = l >> 4;
  const int wr = w >> 1, wc = w & 1;

  f32x4 acc[4][4];
#pragma unroll
  for (int rf = 0; rf < 4; ++rf)
#pragma unroll
    for (int cf = 0; cf < 4; ++cf) { f32x4 z = {0.f,0.f,0.f,0.f}; acc[rf][cf] = z; }

  for (int kc = 0; kc < 4; ++kc) {
    const int kb = kc * 64;
#pragma unroll
    for (int i = 0; i < 16; ++i) {
      const unsigned short* g = gsrc + (size_t)(gbase + i * 8 + segc) * FEAT + kb + kc8l * 8;
      gload_lds16(g, lbase + i * 1024);
    }
    __syncthreads();
#pragma unroll
    for (int ks = 0; ks < 2; ++ks) {
      const int kc8 = ks * 4 + lk;
      const int sA = (kc8 ^ (lc & 7)) * 16;
      bf16x8 ah[4], al[4], bh[4], bl[4];
#pragma unroll
      for (int rf = 0; rf < 4; ++rf) {
        int off = (wr * 64 + rf * 16 + lc) * 128 + sA;
        ah[rf] = *(const bf16x8*)(smem + 32768 + off);
        al[rf] = *(const bf16x8*)(smem + 49152 + off);
      }
#pragma unroll
      for (int cf = 0; cf < 4; ++cf) {
        int off = (wc * 64 + cf * 16 + lc) * 128 + sA;
        bh[cf] = *(const bf16x8*)(smem + off);
        bl[cf] = *(const bf16x8*)(smem + 16384 + off);
      }
#pragma unroll
      for (int rf = 0; rf < 4; ++rf)
#pragma unroll
        for (int cf = 0; cf < 4; ++cf) {
          acc[rf][cf] = __builtin_amdgcn_mfma_f32_16x16x32_bf16(ah[rf], bh[cf], acc[rf][cf], 0, 0, 0);
          acc[rf][cf] = __builtin_amdgcn_mfma_f32_16x16x32_bf16(ah[rf], bl[cf], acc[rf][cf], 0, 0, 0);
          acc[rf][cf] = __builtin_amdgcn_mfma_f32_16x16x32_bf16(al[rf], bh[cf], acc[rf][cf], 0, 0, 0);
        }
    }
    __syncthreads();
  }

  // epilogue: z = min(30*rn*(acc+cb), cap); sum exp(z-30) over this tile's cols
  const float* cb = ws + (islut ? WS_CB1 : WS_CB2);
  const float2* rn2 = (const float2*)(ws + WS_RN2);
  float* red = (float*)smem;   // [128][2]
#pragma unroll
  for (int rf = 0; rf < 4; ++rf) {
    float cbv[4];
#pragma unroll
    for (int r4 = 0; r4 < 4; ++r4)
      cbv[r4] = cb[rowbase + wr * 64 + rf * 16 + lk * 4 + r4];
    float part[4] = {0.f, 0.f, 0.f, 0.f};
#pragma unroll
    for (int cf = 0; cf < 4; ++cf) {
      float2 rc = rn2[colbase + wc * 64 + cf * 16 + lc];
#pragma unroll
      for (int r4 = 0; r4 < 4; ++r4) {
        float z = SCALARV * rc.x * (acc[rf][cf][r4] + cbv[r4]);
        z = fminf(z, rc.y);
        part[r4] += __expf(z - SCALARV);
      }
    }
#pragma unroll
    for (int r4 = 0; r4 < 4; ++r4) {
#pragma unroll
      for (int o = 1; o < 16; o <<= 1) part[r4] += __shfl_xor(part[r4], o);
      if (lc == 0) red[(wr * 64 + rf * 16 + lk * 4 + r4) * 2 + wc] = part[r4];
    }
  }
  __syncthreads();
  if (tid < 128) {
    float val = red[tid * 2] + red[tid * 2 + 1];
    ws[WS_PART + (size_t)(rowbase + tid) * CT + colT] = val;
  }
}

// ---------------- per-row target logit --------------------------------------
__global__ __launch_bounds__(256) void k_target(const int* __restrict__ label,
                                                const float* __restrict__ lut,
                                                float* __restrict__ ws) {
  const int r = blockIdx.x, t = threadIdx.x;
  const int* flags = (const int*)(ws + WS_FLAGS);
  const float2* rn2 = (const float2*)(ws + WS_RN2);
  int y = label[r];
  if (y >= NUM_PIDS) { if (t == 0) ws[WS_ZT + r] = 0.f; return; }
  if (flags[y] == 1) { if (t == 0) ws[WS_ZT + r] = SCALARV; return; }
  float x = ws[WS_Q1 + (size_t)r * FEAT + t] * lut[(size_t)y * FEAT + t];
  for (int o = 32; o; o >>= 1) x += __shfl_down(x, o);
  __shared__ float w4[4];
  if ((t & 63) == 0) w4[t >> 6] = x;
  __syncthreads();
  if (t == 0) {
    float dot = w4[0] + w4[1] + w4[2] + w4[3];
    ws[WS_ZT + r] = SCALARV * rn2[y].x * (dot + ws[WS_CB1 + r]);
  }
}

// ---------------- merge partials -> per-block loss sums ---------------------
__global__ __launch_bounds__(256) void k_loss(const int* __restrict__ label,
                                              float* __restrict__ ws) {
  const int t = threadIdx.x;
  const int r = blockIdx.x * 256 + t;
  const int* flags = (const int*)(ws + WS_FLAGS);
  float ls = 0.f;
  int y = label[r];
  if (y < NUM_PIDS) {
    float ss = 0.f;
    const float* p = ws + WS_PART + (size_t)r * CT;
    for (int c = 0; c < CT; ++c) ss += p[c];
    if (flags[y] == 1) ss += 1.0f - __expf(-2.0f * SCALARV);
    ls = (SCALARV + __logf(ss)) - ws[WS_ZT + r];
  }
  for (int o = 32; o; o >>= 1) ls += __shfl_down(ls, o);
  __shared__ float w4[4];
  if ((t & 63) == 0) w4[t >> 6] = ls;
  __syncthreads();
  if (t == 0) ws[WS_LOSS8 + blockIdx.x] = w4[0] + w4[1] + w4[2] + w4[3];
}

__global__ void k_loss2(float* __restrict__ ws, float* __restrict__ out) {
  if (threadIdx.x == 0) {
    float s = 0.f;
    for (int i = 0; i < 8; ++i) s += ws[WS_LOSS8 + i];
    out[0] = s / (float)BATCH;
  }
}

// ------- momentum scatter: ballot bitmask, bit-exact serial recurrence ------
__global__ __launch_bounds__(256) void k_lutupd(const int* __restrict__ label,
                                                const float* __restrict__ inp,
                                                const float* __restrict__ lut,
                                                float* __restrict__ out_lut) {
  const int r = blockIdx.x, t = threadIdx.x;
  const int y = label[r];
  if (y >= NUM_PIDS) return;
  __shared__ unsigned long long mask[32];     // bit rr: label[rr]==y
  const int wv = t >> 6, ln = t & 63;
#pragma unroll
  for (int it = 0; it < 8; ++it) {
    int i = it * 256 + wv * 64 + ln;
    unsigned long long bal = __ballot(label[i] == y);
    if (ln == 0) mask[it * 4 + wv] = bal;
  }
  __syncthreads();
  const int wr_ = r >> 6, br_ = r & 63;
  // any occurrence after r? (only the last occurrence writes)
  unsigned long long selfbit = 1ull << br_;
  bool after = (mask[wr_] & ~((selfbit - 1) | selfbit)) != 0ull;
  for (int w2 = wr_ + 1; w2 < 32; ++w2) after = after || (mask[w2] != 0ull);
  if (after) return;
  // walk occurrences ascending (includes r itself) — identical f32 sequence
  float f = lut[(size_t)y * FEAT + t];
  for (int w2 = 0; w2 <= wr_; ++w2) {
    unsigned long long m = mask[w2];
    if (w2 == wr_) m &= (selfbit - 1) | selfbit;   // bits <= r
    while (m) {
      int b = __ffsll((unsigned long long)m) - 1;
      m &= m - 1;
      int rr = w2 * 64 + b;
      f = 0.5f * f + 0.5f * inp[(size_t)rr * FEAT + t];
    }
  }
  out_lut[(size_t)y * FEAT + t] = f;
}

// ------- circular-buffer enqueue: rank via ballot popcount ------------------
__global__ __launch_bounds__(256) void k_cqupd(const int* __restrict__ label,
                                               const float* __restrict__ inp,
                                               float* __restrict__ out_cq) {
  const int r = blockIdx.x, t = threadIdx.x;
  if (label[r] != NUM_PIDS) return;
  __shared__ unsigned long long mask[32];     // bit rr: label[rr]==NUM_PIDS
  const int wv = t >> 6, ln = t & 63;
#pragma unroll
  for (int it = 0; it < 8; ++it) {
    int i = it * 256 + wv * 64 + ln;
    unsigned long long bal = __ballot(label[i] == NUM_PIDS);
    if (ln == 0) mask[it * 4 + wv] = bal;
  }
  __syncthreads();
  const int wr_ = r >> 6, br_ = r & 63;
  int rank = 0;
  for (int w2 = 0; w2 < wr_; ++w2) rank += __popcll(mask[w2]);
  rank += __popcll(mask[wr_] & ((1ull << br_) - 1ull));
  out_cq[(size_t)rank * FEAT + t] = inp[(size_t)r * FEAT + t];   // <=2048 < 8192, no wrap
}

extern "C" void kernel_launch(void* const* d_in, const int* in_sizes, int n_in,
                              void* d_out, int out_size, void* d_ws, size_t ws_size,
                              hipStream_t stream) {
  const float* inp = (const float*)d_in[0];
  const int* label = (const int*)d_in[1];
  const float* lut = (const float*)d_in[2];
  const float* cq  = (const float*)d_in[3];
  const float* bnw = (const float*)d_in[4];
  const float* bnb = (const float*)d_in[5];
  float* out = (float*)d_out;
  float* ws  = (float*)d_ws;
  int* flags = (int*)(ws + WS_FLAGS);
  unsigned short* xh = (unsigned short*)(ws + WS_XH);
  unsigned short* xl = (unsigned short*)(ws + WS_XL);
  unsigned short* qp = (unsigned short*)(ws + WS_QP);

  float* out_lut = out + 1;
  float* out_cq  = out + 1 + (size_t)NUM_PIDS * FEAT;

  hipMemcpyAsync(out_lut, lut, (size_t)NUM_PIDS * FEAT * sizeof(float),
                 hipMemcpyDeviceToDevice, stream);
  hipMemcpyAsync(out_cq, cq, (size_t)CQ_SIZE * FEAT * sizeof(float),
                 hipMemcpyDeviceToDevice, stream);

  k_split<<<2048, 256, 0, stream>>>(lut, cq, xh, xl);
  k_stats1<<<NB1, 256, 0, stream>>>(lut, ws, flags);
  k_stats2<<<1, 256, 0, stream>>>(bnw, bnb, ws);
  k_qn<<<BATCH, 256, 0, stream>>>(inp, bnw, bnb, ws, qp);
  k_norms<<<NUM_PIDS + CQ_SIZE, 256, 0, stream>>>(lut, cq, ws);
  k_gemm<<<NWG, 256, 0, stream>>>(xh, xl, qp, ws);
  k_target<<<BATCH, 256, 0, stream>>>(label, lut, ws);
  k_loss<<<8, 256, 0, stream>>>(label, ws);
  k_loss2<<<1, 64, 0, stream>>>(ws, out);
  k_lutupd<<<BATCH, 256, 0, stream>>>(label, inp, lut, out_lut);
  k_cqupd<<<BATCH, 256, 0, stream>>>(label, inp, out_cq);
}

// Round 9
// 373.983 us; speedup vs baseline: 3.5612x; 1.0449x over previous
//
#include <hip/hip_runtime.h>
#include <math.h>

#define NUM_PIDS 30000
#define CQ_SIZE  8192
#define BATCH    2048
#define FEAT     256
#define EPS_BN   1e-5f
#define EPS_NORM 1e-12f
#define SCALARV  30.0f

// padded column space: [0,30000) lut, [30000,30080) pad, [30080,38272) cq
#define LUT_PAD  30080
#define NCOL     38272
#define BC       128
#define LUT_TILES 235     // 30080/128
#define CT       299      // 235 lut tiles + 64 cq tiles
#define RT       16       // 2048/128 row tiles
#define NWG      (CT*RT)  // 4784 = 8*598 (XCD-divisible)
#define NB1      240      // stats blocks, 125 lut rows each (240*125 == 30000)
#define ROWS1    125
#define QPLANE   (BATCH*FEAT)   // ushorts per q plane

// workspace layout (float element offsets)
#define WS_Q1    0
#define WS_CB1   (WS_Q1 + BATCH*FEAT)
#define WS_CB2   (WS_CB1 + BATCH)
#define WS_RN2   (WS_CB2 + BATCH)          // float2 per column: {rn, cap}
#define WS_FLAGS (WS_RN2 + 2*NCOL)         // int32, lut rows only
#define WS_PSUM  (WS_FLAGS + LUT_PAD)
#define WS_PSQ   (WS_PSUM + NB1*FEAT)
#define WS_PCNT  (WS_PSQ + NB1*FEAT)
#define WS_A1    (WS_PCNT + 256)
#define WS_B1    (WS_A1 + FEAT)
#define WS_A2    (WS_B1 + FEAT)
#define WS_B2    (WS_A2 + FEAT)
#define WS_ZT    (WS_B2 + FEAT)
#define WS_PART  (WS_ZT + BATCH)           // [CT][BATCH] floats (transposed)
#define WS_LOSS8 (WS_PART + BATCH*CT)
#define WS_XH    ((WS_LOSS8 + 8 + 3) & ~3) // 16B-aligned; ushort plane
#define WS_XL    (WS_XH + NCOL*FEAT/2)
#define WS_QP    (WS_XL + NCOL*FEAT/2)     // 4 planes: q1h,q1l,q2h,q2l

typedef __bf16 bf16x8 __attribute__((ext_vector_type(8)));
typedef float  f32x4  __attribute__((ext_vector_type(4)));

__device__ __forceinline__ unsigned short f2bf(float f) {
  __bf16 h = (__bf16)f; return __builtin_bit_cast(unsigned short, h);
}
__device__ __forceinline__ float bf2f(unsigned short u) {
  __bf16 h = __builtin_bit_cast(__bf16, u); return (float)h;
}
__device__ __forceinline__ void gload_lds16(const void* g, void* l) {
  __builtin_amdgcn_global_load_lds((__attribute__((address_space(1))) void*)(g),
                                   (__attribute__((address_space(3))) void*)(l), 16, 0, 0);
}
// 8 x 16B per lane: stages 128 rows x 32 halves (8KB) of one plane
__device__ __forceinline__ void stage8(const unsigned short* g, unsigned char* d) {
#pragma unroll
  for (int i = 0; i < 8; ++i)
    gload_lds16(g + (size_t)i * 16 * FEAT, d + i * 1024);
}

// ---------------- stats pass 1 (single-pass: zero rows contribute 0) --------
__global__ __launch_bounds__(256) void k_stats1(const float* __restrict__ lut,
                                                float* __restrict__ ws,
                                                int* __restrict__ flags) {
  const int t = threadIdx.x;
  const int rbase = blockIdx.x * ROWS1;
  __shared__ unsigned char wz[ROWS1 * 4];
  float s = 0.f, sq = 0.f;
  for (int i = 0; i < ROWS1; ++i) {
    float v = lut[(size_t)(rbase + i) * FEAT + t];
    s += v; sq += v * v;                       // bad rows are all-zero: add 0
    unsigned long long bal = __ballot(v != 0.0f);
    if ((t & 63) == 0) wz[i * 4 + (t >> 6)] = (bal != 0ull) ? 1 : 0;
  }
  __syncthreads();
  for (int i = t; i < ROWS1; i += 256) {
    int bad = !(wz[i*4] | wz[i*4+1] | wz[i*4+2] | wz[i*4+3]);
    flags[rbase + i] = bad;
  }
  ws[WS_PSUM + blockIdx.x * FEAT + t] = s;
  ws[WS_PSQ  + blockIdx.x * FEAT + t] = sq;
  if (t == 0) {
    int cnt = 0;
    for (int i = 0; i < ROWS1; ++i)
      cnt += (wz[i*4] | wz[i*4+1] | wz[i*4+2] | wz[i*4+3]) ? 1 : 0;
    ws[WS_PCNT + blockIdx.x] = (float)cnt;
  }
}

// ---------------- stats pass 2 ----------------------------------------------
__global__ __launch_bounds__(256) void k_stats2(const float* __restrict__ bnw,
                                                const float* __restrict__ bnb,
                                                float* __restrict__ ws) {
  const int t = threadIdx.x;
  float2* rn2 = (float2*)(ws + WS_RN2);
  float s = 0.f, sq = 0.f, n = 0.f;
  for (int b = 0; b < NB1; ++b) { s += ws[WS_PSUM + b*FEAT + t]; sq += ws[WS_PSQ + b*FEAT + t]; }
  for (int b = 0; b < NB1; ++b) n += ws[WS_PCNT + b];
  float mean = s / n;
  float var = fmaxf(sq / n - mean * mean, 0.f);
  float istd_b = rsqrtf(var + EPS_BN);
  float rv1 = var * n / (n - 1.f);
  float istd_u = rsqrtf(rv1 + EPS_BN);
  float w = bnw[t], b_ = bnb[t];
  float a1 = istd_b * w, a2 = istd_u * w;
  ws[WS_A1 + t] = a1; ws[WS_B1 + t] = b_ - mean * a1;
  ws[WS_A2 + t] = a2; ws[WS_B2 + t] = b_ - mean * a2;
  if (t < (LUT_PAD - NUM_PIDS)) rn2[NUM_PIDS + t] = make_float2(0.f, -1e30f);
}

// ---------------- raw X -> bf16 hi/lo planes (incl. zero pads) --------------
__global__ __launch_bounds__(256) void k_split(const float* __restrict__ lut,
                                               const float* __restrict__ cq,
                                               unsigned short* __restrict__ xh,
                                               unsigned short* __restrict__ xl) {
  const int stride = gridDim.x * blockDim.x;
  for (int u = blockIdx.x * blockDim.x + threadIdx.x; u < NCOL * 32; u += stride) {
    int col = u >> 5, k8 = (u & 31) * 8;
    float v[8];
    if (col < NUM_PIDS) {
      const float4* p = (const float4*)&lut[(size_t)col * FEAT + k8];
      float4 a = p[0], b = p[1];
      v[0]=a.x; v[1]=a.y; v[2]=a.z; v[3]=a.w; v[4]=b.x; v[5]=b.y; v[6]=b.z; v[7]=b.w;
    } else if (col < LUT_PAD) {
#pragma unroll
      for (int j = 0; j < 8; ++j) v[j] = 0.f;
    } else {
      const float4* p = (const float4*)&cq[(size_t)(col - LUT_PAD) * FEAT + k8];
      float4 a = p[0], b = p[1];
      v[0]=a.x; v[1]=a.y; v[2]=a.z; v[3]=a.w; v[4]=b.x; v[5]=b.y; v[6]=b.z; v[7]=b.w;
    }
    unsigned int hp[4], lp[4];
#pragma unroll
    for (int j = 0; j < 4; ++j) {
      unsigned short h0 = f2bf(v[2*j]),   h1 = f2bf(v[2*j+1]);
      unsigned short l0 = f2bf(v[2*j]   - bf2f(h0));
      unsigned short l1 = f2bf(v[2*j+1] - bf2f(h1));
      hp[j] = (unsigned int)h0 | ((unsigned int)h1 << 16);
      lp[j] = (unsigned int)l0 | ((unsigned int)l1 << 16);
    }
    size_t off = (size_t)col * FEAT + k8;
    *(uint4*)(xh + off) = make_uint4(hp[0], hp[1], hp[2], hp[3]);
    *(uint4*)(xl + off) = make_uint4(lp[0], lp[1], lp[2], lp[3]);
  }
}

// ---------------- qn + q1/q2 planes + per-row scalars -----------------------
__global__ __launch_bounds__(256) void k_qn(const float* __restrict__ inp,
                                            const float* __restrict__ bnw,
                                            const float* __restrict__ bnb,
                                            float* __restrict__ ws,
                                            unsigned short* __restrict__ qp) {
  const int r = blockIdx.x, t = threadIdx.x;
  const float s0 = rsqrtf(1.0f + EPS_BN);
  float v = inp[(size_t)r * FEAT + t];
  float bn = v * (bnw[t] * s0) + bnb[t];
  float x = bn * bn;
  for (int o = 32; o; o >>= 1) x += __shfl_down(x, o);
  __shared__ float w4[4];
  __shared__ float w8[8];
  if ((t & 63) == 0) w4[t >> 6] = x;
  __syncthreads();
  float nsq = w4[0] + w4[1] + w4[2] + w4[3];
  float rinv = 1.0f / fmaxf(sqrtf(nsq), EPS_NORM);
  float qn = bn * rinv;
  float y1 = qn * ws[WS_B1 + t], y2 = qn * ws[WS_B2 + t];
  for (int o = 32; o; o >>= 1) { y1 += __shfl_down(y1, o); y2 += __shfl_down(y2, o); }
  if ((t & 63) == 0) { w8[t >> 6] = y1; w8[4 + (t >> 6)] = y2; }
  float q1 = qn * ws[WS_A1 + t], q2 = qn * ws[WS_A2 + t];
  ws[WS_Q1 + (size_t)r * FEAT + t] = q1;
  size_t o1 = (size_t)r * FEAT + t;
  unsigned short h1 = f2bf(q1), h2 = f2bf(q2);
  qp[0*QPLANE + o1] = h1;
  qp[1*QPLANE + o1] = f2bf(q1 - bf2f(h1));
  qp[2*QPLANE + o1] = h2;
  qp[3*QPLANE + o1] = f2bf(q2 - bf2f(h2));
  __syncthreads();
  if (t == 0) {
    ws[WS_CB1 + r] = w8[0] + w8[1] + w8[2] + w8[3];
    ws[WS_CB2 + r] = w8[4] + w8[5] + w8[6] + w8[7];
  }
}

// ------- per-column {rn, cap}: one wave per row, float4 loads ---------------
__global__ __launch_bounds__(256) void k_norms(const float* __restrict__ lut,
                                               const float* __restrict__ cq,
                                               float* __restrict__ ws) {
  const int row = blockIdx.x * 4 + (threadIdx.x >> 6);
  const int ln = threadIdx.x & 63;
  if (row >= NUM_PIDS + CQ_SIZE) return;
  float2* rn2 = (float2*)(ws + WS_RN2);
  const float* src; const float* av; const float* bv; int cidx;
  if (row < NUM_PIDS) {
    src = lut + (size_t)row * FEAT; av = ws + WS_A1; bv = ws + WS_B1; cidx = row;
  } else {
    int q = row - NUM_PIDS;
    src = cq + (size_t)q * FEAT; av = ws + WS_A2; bv = ws + WS_B2; cidx = LUT_PAD + q;
  }
  float4 x = ((const float4*)src)[ln];
  float4 a = ((const float4*)av)[ln];
  float4 b = ((const float4*)bv)[ln];
  bool nz = (x.x != 0.f) || (x.y != 0.f) || (x.z != 0.f) || (x.w != 0.f);
  unsigned long long bal = __ballot(nz);
  float t0 = a.x*x.x + b.x, t1 = a.y*x.y + b.y, t2 = a.z*x.z + b.z, t3 = a.w*x.w + b.w;
  float ssum = t0*t0 + t1*t1 + t2*t2 + t3*t3;
  for (int o = 32; o; o >>= 1) ssum += __shfl_xor(ssum, o);
  if (ln == 0) {
    // bad column: raw row all-zero -> acc=0; rn=0 gives z=0, cap=-30 -> exact -30 logit
    rn2[cidx] = (bal == 0ull) ? make_float2(0.f, -SCALARV)
                              : make_float2(1.0f / fmaxf(sqrtf(ssum), EPS_NORM), 1e30f);
  }
}

// -------- MFMA GEMM: BK=32 double-buffer, counted vmcnt(8), fixed-max-30 ----
__global__ __launch_bounds__(256) void k_gemm(const unsigned short* __restrict__ xh,
                                              const unsigned short* __restrict__ xl,
                                              const unsigned short* __restrict__ qp,
                                              float* __restrict__ ws) {
  // plane p at p*16384, buffer b at +b*8192; rows of 32 halves (64B)
  __shared__ __align__(16) unsigned char smem[65536];
  const int tid = threadIdx.x;
  const int w = tid >> 6, l = tid & 63;
  const int bid = blockIdx.x;
  const int sid = (bid & 7) * (NWG / 8) + (bid >> 3);   // bijective XCD swizzle
  const int colT = sid >> 4, rowT = sid & 15;
  const bool islut = colT < LUT_TILES;
  const int colbase = colT * BC;
  const int rowbase = rowT * 128;

  const unsigned short* qh = qp + (islut ? 0 : 2) * QPLANE;
  const unsigned short* ql = qh + QPLANE;

  const unsigned short* gsrc;
  unsigned char* lbase;
  int gbase;
  if (w == 0)      { gsrc = xh; lbase = smem;         gbase = colbase; }
  else if (w == 1) { gsrc = xl; lbase = smem + 16384; gbase = colbase; }
  else if (w == 2) { gsrc = qh; lbase = smem + 32768; gbase = rowbase; }
  else             { gsrc = ql; lbase = smem + 49152; gbase = rowbase; }

  // staging: lane l -> row (l>>2) (+16 per instr); LDS slot l&3 holds
  // global k-chunk (l&3)^((l>>4)&3)  [inverse swizzle on SOURCE, linear dest]
  const int kchunk = (l & 3) ^ ((l >> 4) & 3);
  const unsigned short* gp = gsrc + (size_t)(gbase + (l >> 2)) * FEAT + kchunk * 8;

  const int lc = l & 15, lk = l >> 4;
  const int wr = w >> 1, wc = w & 1;
  const int roff = (lk ^ ((lc >> 2) & 3)) * 16;  // swizzled byte offset of k-chunk lk

  f32x4 acc[4][4];
#pragma unroll
  for (int rf = 0; rf < 4; ++rf)
#pragma unroll
    for (int cf = 0; cf < 4; ++cf) { f32x4 z = {0.f,0.f,0.f,0.f}; acc[rf][cf] = z; }

  stage8(gp, lbase);                      // prologue: step 0 -> buf 0
  for (int s = 0; s < 8; ++s) {
    const int cur = s & 1;
    if (s < 7) {
      stage8(gp + (s + 1) * 32, lbase + (cur ^ 1) * 8192);   // issue next step
      asm volatile("s_waitcnt vmcnt(8)" ::: "memory");       // drain CURRENT only
    } else {
      asm volatile("s_waitcnt vmcnt(0)" ::: "memory");
    }
    __builtin_amdgcn_s_barrier();         // publish all planes' current buffers
    __builtin_amdgcn_sched_barrier(0);
    bf16x8 ah[4], al[4], bh[4], bl[4];
#pragma unroll
    for (int rf = 0; rf < 4; ++rf) {
      int off = cur * 8192 + (wr * 64 + rf * 16 + lc) * 64 + roff;
      ah[rf] = *(const bf16x8*)(smem + 32768 + off);
      al[rf] = *(const bf16x8*)(smem + 49152 + off);
    }
#pragma unroll
    for (int cf = 0; cf < 4; ++cf) {
      int off = cur * 8192 + (wc * 64 + cf * 16 + lc) * 64 + roff;
      bh[cf] = *(const bf16x8*)(smem + off);
      bl[cf] = *(const bf16x8*)(smem + 16384 + off);
    }
#pragma unroll
    for (int rf = 0; rf < 4; ++rf)
#pragma unroll
      for (int cf = 0; cf < 4; ++cf) {
        acc[rf][cf] = __builtin_amdgcn_mfma_f32_16x16x32_bf16(ah[rf], bh[cf], acc[rf][cf], 0, 0, 0);
        acc[rf][cf] = __builtin_amdgcn_mfma_f32_16x16x32_bf16(ah[rf], bl[cf], acc[rf][cf], 0, 0, 0);
        acc[rf][cf] = __builtin_amdgcn_mfma_f32_16x16x32_bf16(al[rf], bh[cf], acc[rf][cf], 0, 0, 0);
      }
    if (s < 7) __builtin_amdgcn_s_barrier();   // reads of cur done before overwrite
  }

  // epilogue: z = min(30*rn*(acc+cb), cap); sum exp(z-30) over this tile's cols
  const float* cb = ws + (islut ? WS_CB1 : WS_CB2);
  const float2* rn2 = (const float2*)(ws + WS_RN2);
  float* red = (float*)smem;   // [128][2] — disjoint from step-7 (buf1) regions
#pragma unroll
  for (int rf = 0; rf < 4; ++rf) {
    float cbv[4];
#pragma unroll
    for (int r4 = 0; r4 < 4; ++r4)
      cbv[r4] = cb[rowbase + wr * 64 + rf * 16 + lk * 4 + r4];
    float part[4] = {0.f, 0.f, 0.f, 0.f};
#pragma unroll
    for (int cf = 0; cf < 4; ++cf) {
      float2 rc = rn2[colbase + wc * 64 + cf * 16 + lc];
#pragma unroll
      for (int r4 = 0; r4 < 4; ++r4) {
        float z = SCALARV * rc.x * (acc[rf][cf][r4] + cbv[r4]);
        z = fminf(z, rc.y);
        part[r4] += __expf(z - SCALARV);
      }
    }
#pragma unroll
    for (int r4 = 0; r4 < 4; ++r4) {
#pragma unroll
      for (int o = 1; o < 16; o <<= 1) part[r4] += __shfl_xor(part[r4], o);
      if (lc == 0) red[(wr * 64 + rf * 16 + lk * 4 + r4) * 2 + wc] = part[r4];
    }
  }
  __syncthreads();
  if (tid < 128) {
    float val = red[tid * 2] + red[tid * 2 + 1];
    ws[WS_PART + (size_t)colT * BATCH + rowbase + tid] = val;   // [CT][BATCH]
  }
}

// ---------------- per-row target logit --------------------------------------
__global__ __launch_bounds__(256) void k_target(const int* __restrict__ label,
                                                const float* __restrict__ lut,
                                                float* __restrict__ ws) {
  const int r = blockIdx.x, t = threadIdx.x;
  const int* flags = (const int*)(ws + WS_FLAGS);
  const float2* rn2 = (const float2*)(ws + WS_RN2);
  int y = label[r];
  if (y >= NUM_PIDS) { if (t == 0) ws[WS_ZT + r] = 0.f; return; }
  if (flags[y] == 1) { if (t == 0) ws[WS_ZT + r] = SCALARV; return; }
  float x = ws[WS_Q1 + (size_t)r * FEAT + t] * lut[(size_t)y * FEAT + t];
  for (int o = 32; o; o >>= 1) x += __shfl_down(x, o);
  __shared__ float w4[4];
  if ((t & 63) == 0) w4[t >> 6] = x;
  __syncthreads();
  if (t == 0) {
    float dot = w4[0] + w4[1] + w4[2] + w4[3];
    ws[WS_ZT + r] = SCALARV * rn2[y].x * (dot + ws[WS_CB1 + r]);
  }
}

// ---------------- merge partials -> per-block loss sums ---------------------
__global__ __launch_bounds__(256) void k_loss(const int* __restrict__ label,
                                              float* __restrict__ ws) {
  const int t = threadIdx.x;
  const int r = blockIdx.x * 256 + t;
  const int* flags = (const int*)(ws + WS_FLAGS);
  float ls = 0.f;
  int y = label[r];
  if (y < NUM_PIDS) {
    float ss = 0.f;
    const float* p = ws + WS_PART;
    for (int c = 0; c < CT; ++c) ss += p[(size_t)c * BATCH + r];   // coalesced
    if (flags[y] == 1) ss += 1.0f - __expf(-2.0f * SCALARV);
    ls = (SCALARV + __logf(ss)) - ws[WS_ZT + r];
  }
  for (int o = 32; o; o >>= 1) ls += __shfl_down(ls, o);
  __shared__ float w4[4];
  if ((t & 63) == 0) w4[t >> 6] = ls;
  __syncthreads();
  if (t == 0) ws[WS_LOSS8 + blockIdx.x] = w4[0] + w4[1] + w4[2] + w4[3];
}

__global__ void k_loss2(float* __restrict__ ws, float* __restrict__ out) {
  if (threadIdx.x == 0) {
    float s = 0.f;
    for (int i = 0; i < 8; ++i) s += ws[WS_LOSS8 + i];
    out[0] = s / (float)BATCH;
  }
}

// ------- momentum scatter: ballot bitmask, bit-exact serial recurrence ------
__global__ __launch_bounds__(256) void k_lutupd(const int* __restrict__ label,
                                                const float* __restrict__ inp,
                                                const float* __restrict__ lut,
                                                float* __restrict__ out_lut) {
  const int r = blockIdx.x, t = threadIdx.x;
  const int y = label[r];
  if (y >= NUM_PIDS) return;
  __shared__ unsigned long long mask[32];     // bit rr: label[rr]==y
  const int wv = t >> 6, ln = t & 63;
#pragma unroll
  for (int it = 0; it < 8; ++it) {
    int i = it * 256 + wv * 64 + ln;
    unsigned long long bal = __ballot(label[i] == y);
    if (ln == 0) mask[it * 4 + wv] = bal;
  }
  __syncthreads();
  const int wr_ = r >> 6, br_ = r & 63;
  unsigned long long selfbit = 1ull << br_;
  bool after = (mask[wr_] & ~((selfbit - 1) | selfbit)) != 0ull;
  for (int w2 = wr_ + 1; w2 < 32; ++w2) after = after || (mask[w2] != 0ull);
  if (after) return;                          // only last occurrence writes
  float f = lut[(size_t)y * FEAT + t];
  for (int w2 = 0; w2 <= wr_; ++w2) {
    unsigned long long m = mask[w2];
    if (w2 == wr_) m &= (selfbit - 1) | selfbit;   // bits <= r
    while (m) {
      int b = __ffsll((unsigned long long)m) - 1;
      m &= m - 1;
      int rr = w2 * 64 + b;
      f = 0.5f * f + 0.5f * inp[(size_t)rr * FEAT + t];
    }
  }
  out_lut[(size_t)y * FEAT + t] = f;
}

// ------- circular-buffer enqueue: rank via ballot popcount ------------------
__global__ __launch_bounds__(256) void k_cqupd(const int* __restrict__ label,
                                               const float* __restrict__ inp,
                                               float* __restrict__ out_cq) {
  const int r = blockIdx.x, t = threadIdx.x;
  if (label[r] != NUM_PIDS) return;
  __shared__ unsigned long long mask[32];     // bit rr: label[rr]==NUM_PIDS
  const int wv = t >> 6, ln = t & 63;
#pragma unroll
  for (int it = 0; it < 8; ++it) {
    int i = it * 256 + wv * 64 + ln;
    unsigned long long bal = __ballot(label[i] == NUM_PIDS);
    if (ln == 0) mask[it * 4 + wv] = bal;
  }
  __syncthreads();
  const int wr_ = r >> 6, br_ = r & 63;
  int rank = 0;
  for (int w2 = 0; w2 < wr_; ++w2) rank += __popcll(mask[w2]);
  rank += __popcll(mask[wr_] & ((1ull << br_) - 1ull));
  out_cq[(size_t)rank * FEAT + t] = inp[(size_t)r * FEAT + t];   // <=2048 < 8192, no wrap
}

extern "C" void kernel_launch(void* const* d_in, const int* in_sizes, int n_in,
                              void* d_out, int out_size, void* d_ws, size_t ws_size,
                              hipStream_t stream) {
  const float* inp = (const float*)d_in[0];
  const int* label = (const int*)d_in[1];
  const float* lut = (const float*)d_in[2];
  const float* cq  = (const float*)d_in[3];
  const float* bnw = (const float*)d_in[4];
  const float* bnb = (const float*)d_in[5];
  float* out = (float*)d_out;
  float* ws  = (float*)d_ws;
  int* flags = (int*)(ws + WS_FLAGS);
  unsigned short* xh = (unsigned short*)(ws + WS_XH);
  unsigned short* xl = (unsigned short*)(ws + WS_XL);
  unsigned short* qp = (unsigned short*)(ws + WS_QP);

  float* out_lut = out + 1;
  float* out_cq  = out + 1 + (size_t)NUM_PIDS * FEAT;

  hipMemcpyAsync(out_lut, lut, (size_t)NUM_PIDS * FEAT * sizeof(float),
                 hipMemcpyDeviceToDevice, stream);
  hipMemcpyAsync(out_cq, cq, (size_t)CQ_SIZE * FEAT * sizeof(float),
                 hipMemcpyDeviceToDevice, stream);

  k_split<<<2048, 256, 0, stream>>>(lut, cq, xh, xl);
  k_stats1<<<NB1, 256, 0, stream>>>(lut, ws, flags);
  k_stats2<<<1, 256, 0, stream>>>(bnw, bnb, ws);
  k_qn<<<BATCH, 256, 0, stream>>>(inp, bnw, bnb, ws, qp);
  k_norms<<<(NUM_PIDS + CQ_SIZE + 3) / 4, 256, 0, stream>>>(lut, cq, ws);
  k_gemm<<<NWG, 256, 0, stream>>>(xh, xl, qp, ws);
  k_target<<<BATCH, 256, 0, stream>>>(label, lut, ws);
  k_loss<<<8, 256, 0, stream>>>(label, ws);
  k_loss2<<<1, 64, 0, stream>>>(ws, out);
  k_lutupd<<<BATCH, 256, 0, stream>>>(label, inp, lut, out_lut);
  k_cqupd<<<BATCH, 256, 0, stream>>>(label, inp, out_cq);
}